// Round 18
// baseline (1419.005 us; speedup 1.0000x reference)
//
#include <hip/hip_runtime.h>

#define S 2048
#define DD 64
#define NH 32           // B*H
#define NW 8            // waves per block
#define KSLICE 256      // k columns per wave
#define NT 16           // 16-wide k tiles per wave

typedef float f32x4 __attribute__((ext_vector_type(4)));
typedef float f32x2 __attribute__((ext_vector_type(2)));
typedef unsigned int u32x4 __attribute__((ext_vector_type(4)));
typedef short bf16x8 __attribute__((ext_vector_type(8)));

__device__ inline unsigned int packsplit(float x){
  unsigned int u = __float_as_uint(x);
  unsigned int h = u >> 16;
  float rem = x - __uint_as_float(h << 16);
  unsigned int l = __float_as_uint(rem) >> 16;
  return (h << 16) | l;
}
__device__ inline void split2(float x, short &hi, short &lo){
  unsigned int p = packsplit(x);
  hi = (short)(p >> 16); lo = (short)(p & 0xFFFFu);
}
__device__ inline f32x4 ntload4(const float* p){
  return __builtin_nontemporal_load(reinterpret_cast<const f32x4*>(p));
}
__device__ inline f32x2 ntload2(const float* p){
  return __builtin_nontemporal_load(reinterpret_cast<const f32x2*>(p));
}

// ---- pre-pack kernels ----
__global__ void pack_k_kernel(const float* __restrict__ in, unsigned int* __restrict__ out, int n4){
  int i = blockIdx.x * 256 + threadIdx.x;
  if (i < n4){
    f32x4 x = ntload4(in + 4*(size_t)i);
    u32x4 p;
    p.x = packsplit(x.x); p.y = packsplit(x.y);
    p.z = packsplit(x.z); p.w = packsplit(x.w);
    reinterpret_cast<u32x4*>(out)[i] = p;
  }
}

__global__ void pack_vt_kernel(const float* __restrict__ v, unsigned int* __restrict__ vt){
  const int head = blockIdx.x >> 5;
  const int s0   = (blockIdx.x & 31) * 64;
  const float* vh = v + (size_t)head * S * DD;
  unsigned int* vth = vt + (size_t)head * DD * S;
  __shared__ unsigned int tile[64][65];
  const int tid = threadIdx.x;
  for (int i = tid; i < 64*64; i += 256){
    int s = i >> 6, d = i & 63;
    tile[d][s] = packsplit(__builtin_nontemporal_load(&vh[(size_t)(s0 + s) * DD + d]));
  }
  __syncthreads();
  for (int i = tid; i < 64*64; i += 256){
    int d = i >> 6, s = i & 63;
    vth[(size_t)d * S + s0 + s] = tile[d][s];
  }
}

// ==== Fused attention v2 + destination pre-read:
// weight-store lines are pulled into L2 by a dummy read immediately before
// the store burst, converting fresh-line streaming writes (3-5x amplified,
// r11-r17 evidence) into clean in-place writes (K2 evidence: exactly-ideal
// WRITE when lines are resident). ====
template<bool PACKED>
__global__ __launch_bounds__(512, 4)   // <=128 regs/wave: 2 blocks/CU
void attn_fused_kernel(const float* __restrict__ q, const float* __restrict__ k,
                       const float* __restrict__ v, const float* __restrict__ bias,
                       const float* __restrict__ gb,
                       const unsigned int* __restrict__ kp,
                       const unsigned int* __restrict__ vtp,
                       float* __restrict__ out, float* __restrict__ wout)
{
  const int head = blockIdx.y;
  const int q0   = blockIdx.x * 16;
  const int tid  = threadIdx.x;
  const int wid  = tid >> 6;
  const int lane = tid & 63;
  const int lr   = lane & 15;
  const int lg   = lane >> 4;

  const float* qh = q    + (size_t)head * S * DD;
  const float* kh = k    + (size_t)head * S * DD;
  const float* vh = v    + (size_t)head * S * DD;
  const float* bh = bias + (size_t)head * S * S;
  const float* gh = gb   + (size_t)head * S * S;
  const unsigned int* kph  = kp  + (size_t)head * S * DD;
  const unsigned int* vtph = vtp + (size_t)head * DD * S;
  float* oh = out  + (size_t)head * S * DD;
  float* wh = wout + (size_t)head * S * S;

  __shared__ float buf[NW][16][132];   // 67.6 KB, reused: stream / st / sW / sO
  __shared__ float redm[NW][16];
  __shared__ float redl[NW][16];

  const int kw0 = wid * KSLICE;
  f32x4 acc[NT];

  // ---- Phase 0: acc = bias - 0.5*g^2 via wave-private row-major streaming.
  {
    const float* b0p = bh + (size_t)q0 * S + kw0;
    const float* g0p = gh + (size_t)q0 * S + kw0;
#pragma unroll 1
    for (int h = 0; h < 2; ++h){
#pragma unroll
      for (int rr = 0; rr < 16; ++rr){
        f32x2 x = ntload2(b0p + (size_t)rr * S + h*128 + 2*lane);
        *reinterpret_cast<f32x2*>(&buf[wid][rr][2*lane]) = x;
      }
      asm volatile("s_waitcnt lgkmcnt(0)" ::: "memory");
      __builtin_amdgcn_sched_barrier(0);
#pragma unroll
      for (int t8 = 0; t8 < 8; ++t8)
        acc[h*8 + t8] = *reinterpret_cast<const f32x4*>(&buf[wid][lr][16*t8 + lg*4]);
      asm volatile("s_waitcnt lgkmcnt(0)" ::: "memory");
      __builtin_amdgcn_sched_barrier(0);
#pragma unroll
      for (int rr = 0; rr < 16; ++rr){
        f32x2 x = ntload2(g0p + (size_t)rr * S + h*128 + 2*lane);
        *reinterpret_cast<f32x2*>(&buf[wid][rr][2*lane]) = x;
      }
      asm volatile("s_waitcnt lgkmcnt(0)" ::: "memory");
      __builtin_amdgcn_sched_barrier(0);
#pragma unroll
      for (int t8 = 0; t8 < 8; ++t8){
        f32x4 g4 = *reinterpret_cast<const f32x4*>(&buf[wid][lr][16*t8 + lg*4]);
#pragma unroll
        for (int r = 0; r < 4; ++r)
          acc[h*8 + t8][r] -= 0.5f * g4[r] * g4[r];
      }
      asm volatile("s_waitcnt lgkmcnt(0)" ::: "memory");
      __builtin_amdgcn_sched_barrier(0);
    }
  }

  // ---- Q fragments (B operand: lane holds Q[q0+lr][32ks + lg*8+j]), pre-scaled
  bf16x8 qhi[2], qlo[2];
  {
    const float* qrow = qh + (size_t)(q0 + lr) * DD;
#pragma unroll
    for (int ks = 0; ks < 2; ++ks){
      float4 a = *reinterpret_cast<const float4*>(qrow + ks*32 + lg*8);
      float4 b = *reinterpret_cast<const float4*>(qrow + ks*32 + lg*8 + 4);
      float f[8] = {a.x,a.y,a.z,a.w,b.x,b.y,b.z,b.w};
#pragma unroll
      for (int j = 0; j < 8; ++j){
        short h, l2; split2(f[j] * 0.125f, h, l2);
        qhi[ks][j] = h; qlo[ks][j] = l2;
      }
    }
  }

  // ---- Phase 1: QK^T accumulates on top of bias-initialized acc
#pragma unroll 2
  for (int t = 0; t < NT; ++t){
    const int kbase = kw0 + 16*t;
    bf16x8 khi[2], klo[2];
    if constexpr (PACKED){
      const unsigned int* kr = kph + (size_t)(kbase + lr) * DD;
#pragma unroll
      for (int ks = 0; ks < 2; ++ks){
        uint4 pa = *reinterpret_cast<const uint4*>(kr + ks*32 + lg*8);
        uint4 pb = *reinterpret_cast<const uint4*>(kr + ks*32 + lg*8 + 4);
        unsigned int pw[8] = {pa.x,pa.y,pa.z,pa.w,pb.x,pb.y,pb.z,pb.w};
#pragma unroll
        for (int j = 0; j < 8; ++j){
          khi[ks][j] = (short)(pw[j] >> 16);
          klo[ks][j] = (short)(pw[j] & 0xFFFFu);
        }
      }
    } else {
      const float* krow = kh + (size_t)(kbase + lr) * DD;
#pragma unroll
      for (int ks = 0; ks < 2; ++ks){
        float4 a = *reinterpret_cast<const float4*>(krow + ks*32 + lg*8);
        float4 b = *reinterpret_cast<const float4*>(krow + ks*32 + lg*8 + 4);
        float f[8] = {a.x,a.y,a.z,a.w,b.x,b.y,b.z,b.w};
#pragma unroll
        for (int j = 0; j < 8; ++j){
          short h, l2; split2(f[j], h, l2);
          khi[ks][j] = h; klo[ks][j] = l2;
        }
      }
    }
#pragma unroll
    for (int ks = 0; ks < 2; ++ks){
      acc[t] = __builtin_amdgcn_mfma_f32_16x16x32_bf16(klo[ks], qhi[ks], acc[t], 0,0,0);
      acc[t] = __builtin_amdgcn_mfma_f32_16x16x32_bf16(khi[ks], qlo[ks], acc[t], 0,0,0);
      acc[t] = __builtin_amdgcn_mfma_f32_16x16x32_bf16(khi[ks], qhi[ks], acc[t], 0,0,0);
    }
  }

  // ---- Phase 2: softmax. Row q0+lr fully owned along (lg, r, t, wave).
  float mrow;
  {
    float mm = -3.4e38f;
#pragma unroll
    for (int t = 0; t < NT; ++t)
#pragma unroll
      for (int r = 0; r < 4; ++r) mm = fmaxf(mm, acc[t][r]);
    mm = fmaxf(mm, __shfl_xor(mm, 16, 64));
    mm = fmaxf(mm, __shfl_xor(mm, 32, 64));
    if (lane < 16) redm[wid][lane] = mm;
  }
  __syncthreads();
  {
    float mm = redm[0][lr];
#pragma unroll
    for (int w = 1; w < NW; ++w) mm = fmaxf(mm, redm[w][lr]);
    mrow = mm;
  }

  float inv;
  {
    float s = 0.f;
#pragma unroll
    for (int t = 0; t < NT; ++t)
#pragma unroll
      for (int r = 0; r < 4; ++r){
        float e = __expf(acc[t][r] - mrow);
        acc[t][r] = e;
        s += e;
      }
    s += __shfl_xor(s, 16, 64);
    s += __shfl_xor(s, 32, 64);
    if (lane < 16) redl[wid][lane] = s;
    __syncthreads();
    float tot = 0.f;
#pragma unroll
    for (int w = 0; w < NW; ++w) tot += redl[w][lr];
    inv = 1.0f / tot;
  }

  // ---- Phase 3: weights out via barrier-ordered LDS transpose + DEST PRE-READ.
  float (*st)[8][260] = reinterpret_cast<float(*)[8][260]>(&buf[0][0][0]);
#pragma unroll 1
  for (int p = 0; p < 2; ++p){
    if ((lr >> 3) == p){
#pragma unroll
      for (int t = 0; t < NT; ++t){
        f32x4 w4;
#pragma unroll
        for (int r = 0; r < 4; ++r) w4[r] = acc[t][r] * inv;
        *reinterpret_cast<f32x4*>(&st[wid][lr & 7][16*t + lg*4]) = w4;
      }
    }
    __syncthreads();
    // pre-read destination lines into L2 (values folded + kept alive, discarded)
    {
      float keep = 0.f;
#pragma unroll
      for (int j = 0; j < 8; ++j){
        const int row8 = (j + wid) & 7;
        f32x4 pr = *reinterpret_cast<const f32x4*>(
            wh + (size_t)(q0 + p*8 + row8) * S + wid*256 + lane*4);
        keep += pr[0] + pr[1] + pr[2] + pr[3];
      }
      asm volatile("" :: "v"(keep));
    }
#pragma unroll
    for (int j = 0; j < 8; ++j){
      const int row8 = (j + wid) & 7;
      f32x4 v4 = *reinterpret_cast<const f32x4*>(&st[wid][row8][lane*4]);
      *reinterpret_cast<f32x4*>(wh + (size_t)(q0 + p*8 + row8) * S + wid*256 + lane*4) = v4;
    }
    __syncthreads();
  }

  // ---- Phase 4: PV from in-register weights (sW aliases buf)
  unsigned int (*sW)[16][68] = reinterpret_cast<unsigned int(*)[16][68]>(&buf[0][0][0]);
  f32x4 oacc[4];
#pragma unroll
  for (int n = 0; n < 4; ++n) oacc[n] = (f32x4){0.f,0.f,0.f,0.f};

#pragma unroll 1
  for (int c = 0; c < 4; ++c){
#pragma unroll
    for (int tt = 0; tt < 4; ++tt){
      const int t = 4*c + tt;
      u32x4 pw;
#pragma unroll
      for (int r = 0; r < 4; ++r)
        pw[r] = packsplit(acc[t][r] * inv);
      *reinterpret_cast<u32x4*>(&sW[wid][lr][16*tt + lg*4]) = pw;
    }
    const int kc = kw0 + 64*c;
#pragma unroll
    for (int ks = 0; ks < 2; ++ks){
      uint4 pa0 = *reinterpret_cast<const uint4*>(&sW[wid][lr][32*ks + lg*8]);
      uint4 pa1 = *reinterpret_cast<const uint4*>(&sW[wid][lr][32*ks + lg*8 + 4]);
      unsigned int pa[8] = {pa0.x,pa0.y,pa0.z,pa0.w,pa1.x,pa1.y,pa1.z,pa1.w};
      bf16x8 ahi, alo;
#pragma unroll
      for (int j = 0; j < 8; ++j){
        ahi[j] = (short)(pa[j] >> 16);
        alo[j] = (short)(pa[j] & 0xFFFFu);
      }
#pragma unroll
      for (int n = 0; n < 4; ++n){
        bf16x8 bhi, blo;
        if constexpr (PACKED){
          const unsigned int* vrow = vtph + (size_t)(16*n + lr) * S + kc + 32*ks + lg*8;
          uint4 pv0 = *reinterpret_cast<const uint4*>(vrow);
          uint4 pv1 = *reinterpret_cast<const uint4*>(vrow + 4);
          unsigned int pw[8] = {pv0.x,pv0.y,pv0.z,pv0.w,pv1.x,pv1.y,pv1.z,pv1.w};
#pragma unroll
          for (int j = 0; j < 8; ++j){
            bhi[j] = (short)(pw[j] >> 16);
            blo[j] = (short)(pw[j] & 0xFFFFu);
          }
        } else {
#pragma unroll
          for (int j = 0; j < 8; ++j){
            float x = vh[(size_t)(kc + 32*ks + lg*8 + j) * DD + 16*n + lr];
            short h, l2; split2(x, h, l2);
            bhi[j] = h; blo[j] = l2;
          }
        }
        oacc[n] = __builtin_amdgcn_mfma_f32_16x16x32_bf16(alo, bhi, oacc[n], 0,0,0);
        oacc[n] = __builtin_amdgcn_mfma_f32_16x16x32_bf16(ahi, blo, oacc[n], 0,0,0);
        oacc[n] = __builtin_amdgcn_mfma_f32_16x16x32_bf16(ahi, bhi, oacc[n], 0,0,0);
      }
    }
  }

  // ---- Phase 5: cross-wave reduction of out partials (sO aliases buf)
  float (*sO)[16][68] = reinterpret_cast<float(*)[16][68]>(&buf[0][0][0]);
  __syncthreads();
#pragma unroll
  for (int n = 0; n < 4; ++n)
#pragma unroll
    for (int r = 0; r < 4; ++r)
      sO[wid][lg*4 + r][16*n + lr] = oacc[n][r];
  __syncthreads();
#pragma unroll
  for (int i = tid; i < 16*64; i += 512){
    int row = i >> 6, d = i & 63;
    float ssum = 0.f;
#pragma unroll
    for (int wv = 0; wv < NW; ++wv) ssum += sO[wv][row][d];
    oh[(size_t)(q0 + row) * DD + d] = ssum;
  }
}

extern "C" void kernel_launch(void* const* d_in, const int* in_sizes, int n_in,
                              void* d_out, int out_size, void* d_ws, size_t ws_size,
                              hipStream_t stream) {
  const float* q    = (const float*)d_in[0];
  const float* k    = (const float*)d_in[1];
  const float* v    = (const float*)d_in[2];
  const float* bias = (const float*)d_in[3];
  const float* gb   = (const float*)d_in[4];
  float* out  = (float*)d_out;
  float* wout = (float*)d_out + (size_t)NH * S * DD;

  const size_t nelem = (size_t)NH * S * DD;       // 4.19M
  const size_t need  = 2 * nelem * sizeof(unsigned int);

  dim3 grid(S / 16, NH);
  dim3 block(512);

  if (ws_size >= need){
    unsigned int* kp  = (unsigned int*)d_ws;
    unsigned int* vtp = kp + nelem;
    int n4 = (int)(nelem / 4);
    pack_k_kernel<<<(n4 + 255) / 256, 256, 0, stream>>>(k, kp, n4);
    pack_vt_kernel<<<NH * 32, 256, 0, stream>>>(v, vtp);
    attn_fused_kernel<true ><<<grid, block, 0, stream>>>(q, k, v, bias, gb, kp, vtp, out, wout);
  } else {
    attn_fused_kernel<false><<<grid, block, 0, stream>>>(q, k, v, bias, gb, nullptr, nullptr, out, wout);
  }
}

// Round 19
// 1181.491 us; speedup vs baseline: 1.2010x; 1.2010x over previous
//
#include <hip/hip_runtime.h>

#define S 2048
#define DD 64
#define NH 32           // B*H
#define NW 8            // waves per block
#define KSLICE 256      // k columns per wave
#define NT 16           // 16-wide k tiles per wave

typedef float f32x4 __attribute__((ext_vector_type(4)));
typedef unsigned int u32x4 __attribute__((ext_vector_type(4)));
typedef short bf16x8 __attribute__((ext_vector_type(8)));

__device__ inline unsigned int packsplit(float x){
  unsigned int u = __float_as_uint(x);
  unsigned int h = u >> 16;
  float rem = x - __uint_as_float(h << 16);
  unsigned int l = __float_as_uint(rem) >> 16;
  return (h << 16) | l;
}
__device__ inline void split2(float x, short &hi, short &lo){
  unsigned int p = packsplit(x);
  hi = (short)(p >> 16); lo = (short)(p & 0xFFFFu);
}
__device__ inline f32x4 ntload4(const float* p){
  return __builtin_nontemporal_load(reinterpret_cast<const f32x4*>(p));
}
__device__ inline void ntstore4(float* p, f32x4 v){
  __builtin_nontemporal_store(v, reinterpret_cast<f32x4*>(p));
}

// ---- pre-pack kernels ----
__global__ void pack_k_kernel(const float* __restrict__ in, unsigned int* __restrict__ out, int n4){
  int i = blockIdx.x * 256 + threadIdx.x;
  if (i < n4){
    f32x4 x = ntload4(in + 4*(size_t)i);
    u32x4 p;
    p.x = packsplit(x.x); p.y = packsplit(x.y);
    p.z = packsplit(x.z); p.w = packsplit(x.w);
    reinterpret_cast<u32x4*>(out)[i] = p;
  }
}

__global__ void pack_vt_kernel(const float* __restrict__ v, unsigned int* __restrict__ vt){
  const int head = blockIdx.x >> 5;
  const int s0   = (blockIdx.x & 31) * 64;
  const float* vh = v + (size_t)head * S * DD;
  unsigned int* vth = vt + (size_t)head * DD * S;
  __shared__ unsigned int tile[64][65];
  const int tid = threadIdx.x;
  for (int i = tid; i < 64*64; i += 256){
    int s = i >> 6, d = i & 63;
    tile[d][s] = packsplit(__builtin_nontemporal_load(&vh[(size_t)(s0 + s) * DD + d]));
  }
  __syncthreads();
  for (int i = tid; i < 64*64; i += 256){
    int d = i >> 6, s = i & 63;
    vth[(size_t)d * S + s0 + s] = tile[d][s];
  }
}

// ==== K1: QK^T -> scores in standard layout via LDS transpose.
// Store instructions are 1KB contiguous single-row runs (no 16-row scatter).
// Transpose phases explicitly barrier-ordered. ====
template<bool PACKED>
__global__ __launch_bounds__(512, 4)
void qk_scores_kernel(const float* __restrict__ q, const float* __restrict__ k,
                      const unsigned int* __restrict__ kp, float* __restrict__ sc)
{
  const int head = blockIdx.y;
  const int q0   = blockIdx.x * 16;
  const int tid  = threadIdx.x;
  const int wid  = tid >> 6;
  const int lane = tid & 63;
  const int lr   = lane & 15;
  const int lg   = lane >> 4;

  const float* qh = q + (size_t)head * S * DD;
  const float* kh = k + (size_t)head * S * DD;
  const unsigned int* kph = kp + (size_t)head * S * DD;
  float* sh = sc + (size_t)head * S * S;

  __shared__ float st[NW][8][260];   // 66.6 KB: per-wave transpose buffer

  // Q fragments, pre-scaled by 1/sqrt(64)
  bf16x8 qhi[2], qlo[2];
  {
    const float* qrow = qh + (size_t)(q0 + lr) * DD;
#pragma unroll
    for (int ks = 0; ks < 2; ++ks){
      float4 a = *reinterpret_cast<const float4*>(qrow + ks*32 + lg*8);
      float4 b = *reinterpret_cast<const float4*>(qrow + ks*32 + lg*8 + 4);
      float f[8] = {a.x,a.y,a.z,a.w,b.x,b.y,b.z,b.w};
#pragma unroll
      for (int j = 0; j < 8; ++j){
        short h, l2; split2(f[j] * 0.125f, h, l2);
        qhi[ks][j] = h; qlo[ks][j] = l2;
      }
    }
  }

  const int kw0 = wid * KSLICE;
  f32x4 acc[NT];
#pragma unroll
  for (int t = 0; t < NT; ++t) acc[t] = (f32x4){0.f,0.f,0.f,0.f};

#pragma unroll 2
  for (int t = 0; t < NT; ++t){
    const int kbase = kw0 + 16*t;
    bf16x8 khi[2], klo[2];
    if constexpr (PACKED){
      const unsigned int* kr = kph + (size_t)(kbase + lr) * DD;
#pragma unroll
      for (int ks = 0; ks < 2; ++ks){
        uint4 pa = *reinterpret_cast<const uint4*>(kr + ks*32 + lg*8);
        uint4 pb = *reinterpret_cast<const uint4*>(kr + ks*32 + lg*8 + 4);
        unsigned int pw[8] = {pa.x,pa.y,pa.z,pa.w,pb.x,pb.y,pb.z,pb.w};
#pragma unroll
        for (int j = 0; j < 8; ++j){
          khi[ks][j] = (short)(pw[j] >> 16);
          klo[ks][j] = (short)(pw[j] & 0xFFFFu);
        }
      }
    } else {
      const float* krow = kh + (size_t)(kbase + lr) * DD;
#pragma unroll
      for (int ks = 0; ks < 2; ++ks){
        float4 a = *reinterpret_cast<const float4*>(krow + ks*32 + lg*8);
        float4 b = *reinterpret_cast<const float4*>(krow + ks*32 + lg*8 + 4);
        float f[8] = {a.x,a.y,a.z,a.w,b.x,b.y,b.z,b.w};
#pragma unroll
        for (int j = 0; j < 8; ++j){
          short h, l2; split2(f[j], h, l2);
          khi[ks][j] = h; klo[ks][j] = l2;
        }
      }
    }
#pragma unroll
    for (int ks = 0; ks < 2; ++ks){
      acc[t] = __builtin_amdgcn_mfma_f32_16x16x32_bf16(klo[ks], qhi[ks], acc[t], 0,0,0);
      acc[t] = __builtin_amdgcn_mfma_f32_16x16x32_bf16(khi[ks], qlo[ks], acc[t], 0,0,0);
      acc[t] = __builtin_amdgcn_mfma_f32_16x16x32_bf16(khi[ks], qhi[ks], acc[t], 0,0,0);
    }
  }

  // ---- LDS transpose dump: two 8-row passes, barrier-ordered.
  // One store instruction = 64 lanes x 16B = 1KB contiguous in ONE row.
#pragma unroll 1
  for (int p = 0; p < 2; ++p){
    if ((lr >> 3) == p){
#pragma unroll
      for (int t = 0; t < NT; ++t)
        *reinterpret_cast<f32x4*>(&st[wid][lr & 7][16*t + lg*4]) = acc[t];
    }
    __syncthreads();
#pragma unroll
    for (int j = 0; j < 8; ++j){
      const int row8 = (j + wid) & 7;
      f32x4 v4 = *reinterpret_cast<const f32x4*>(&st[wid][row8][lane*4]);
      ntstore4(sh + (size_t)(q0 + p*8 + row8) * S + wid*256 + lane*4, v4);
    }
    __syncthreads();
  }
}

// ==== K2: row softmax of (scores + bias - 0.5*g^2), in-place on w ====
__global__ __launch_bounds__(256, 8)
void softmax_row_kernel(const float* __restrict__ bias, const float* __restrict__ gb,
                        float* __restrict__ w)
{
  const int bid  = (NH * S - 1) - (int)blockIdx.x;   // reverse: catch K1's L3-warm tail
  const int head = bid >> 11;
  const int row  = bid & (S - 1);
  const size_t ro = ((size_t)head * S + row) * S;
  const int tid  = threadIdx.x;
  const int wid  = tid >> 6;
  const int lane = tid & 63;
  const int c0   = tid * 8;

  f32x4 s0 = *reinterpret_cast<const f32x4*>(w + ro + c0);
  f32x4 s1 = *reinterpret_cast<const f32x4*>(w + ro + c0 + 4);
  f32x4 b0 = ntload4(bias + ro + c0);
  f32x4 b1 = ntload4(bias + ro + c0 + 4);
  f32x4 g0 = ntload4(gb + ro + c0);
  f32x4 g1 = ntload4(gb + ro + c0 + 4);

  float x[8];
#pragma unroll
  for (int j = 0; j < 4; ++j){
    x[j]   = s0[j] + b0[j] - 0.5f * g0[j] * g0[j];
    x[4+j] = s1[j] + b1[j] - 0.5f * g1[j] * g1[j];
  }

  __shared__ float redm[4], reds[4];

  float m = x[0];
#pragma unroll
  for (int j = 1; j < 8; ++j) m = fmaxf(m, x[j]);
#pragma unroll
  for (int off = 1; off < 64; off <<= 1) m = fmaxf(m, __shfl_xor(m, off, 64));
  if (lane == 0) redm[wid] = m;
  __syncthreads();
  m = fmaxf(fmaxf(redm[0], redm[1]), fmaxf(redm[2], redm[3]));

  float e[8], s = 0.f;
#pragma unroll
  for (int j = 0; j < 8; ++j){ e[j] = __expf(x[j] - m); s += e[j]; }
#pragma unroll
  for (int off = 1; off < 64; off <<= 1) s += __shfl_xor(s, off, 64);
  if (lane == 0) reds[wid] = s;
  __syncthreads();
  const float inv = 1.0f / (reds[0] + reds[1] + reds[2] + reds[3]);

  f32x4 w0, w1;
#pragma unroll
  for (int j = 0; j < 4; ++j){ w0[j] = e[j] * inv; w1[j] = e[4+j] * inv; }
  *reinterpret_cast<f32x4*>(w + ro + c0)     = w0;
  *reinterpret_cast<f32x4*>(w + ro + c0 + 4) = w1;
}

// ==== K3: out = W x V with LDS-slab staged contiguous weight reads ====
template<bool PACKED>
__global__ __launch_bounds__(512, 4)
void pv_kernel(const float* __restrict__ w, const float* __restrict__ v,
               const unsigned int* __restrict__ vtp, float* __restrict__ out)
{
  const int head = (NH - 1) - blockIdx.y;            // reverse: catch K2's L3 tail
  const int q0   = ((S/16 - 1) - blockIdx.x) * 16;
  const int tid  = threadIdx.x;
  const int wid  = tid >> 6;
  const int lane = tid & 63;
  const int lr   = lane & 15;
  const int lg   = lane >> 4;

  const float* wh = w + (size_t)head * S * S;
  const float* vh = v + (size_t)head * S * DD;
  const unsigned int* vtph = vtp + (size_t)head * DD * S;
  float* oh = out + (size_t)head * S * DD;

  __shared__ float slab[16][516];                    // 33 KB super-chunk stage
  __shared__ unsigned int sW[NW][16][68];            // 34.8 KB packed weights

  f32x4 oacc[4];
#pragma unroll
  for (int n = 0; n < 4; ++n) oacc[n] = (f32x4){0.f,0.f,0.f,0.f};

  const int frow = tid >> 5;                         // fill mapping: row 0..15
  const int fi   = tid & 31;

#pragma unroll 1
  for (int s = 0; s < 4; ++s){
    // cooperative fill: per instruction = 512B contiguous single-row runs
#pragma unroll
    for (int m = 0; m < 4; ++m){
      f32x4 v4 = ntload4(wh + (size_t)(q0 + frow) * S + 512*s + fi*4 + m*128);
      *reinterpret_cast<f32x4*>(&slab[frow][fi*4 + m*128]) = v4;
    }
    __syncthreads();

    // wave wid consumes cols [512s + 64*wid, +64): pack slab -> sW (wave-private)
    const int kc = 512*s + 64*wid;
#pragma unroll
    for (int tt = 0; tt < 4; ++tt){
      f32x4 w4 = *reinterpret_cast<const f32x4*>(&slab[lr][64*wid + 16*tt + lg*4]);
      u32x4 pw;
#pragma unroll
      for (int r = 0; r < 4; ++r) pw[r] = packsplit(w4[r]);
      *reinterpret_cast<u32x4*>(&sW[wid][lr][16*tt + lg*4]) = pw;
    }
#pragma unroll
    for (int ks = 0; ks < 2; ++ks){
      uint4 pa0 = *reinterpret_cast<const uint4*>(&sW[wid][lr][32*ks + lg*8]);
      uint4 pa1 = *reinterpret_cast<const uint4*>(&sW[wid][lr][32*ks + lg*8 + 4]);
      unsigned int pa[8] = {pa0.x,pa0.y,pa0.z,pa0.w,pa1.x,pa1.y,pa1.z,pa1.w};
      bf16x8 ahi, alo;
#pragma unroll
      for (int j = 0; j < 8; ++j){
        ahi[j] = (short)(pa[j] >> 16);
        alo[j] = (short)(pa[j] & 0xFFFFu);
      }
#pragma unroll
      for (int n = 0; n < 4; ++n){
        bf16x8 bhi, blo;
        if constexpr (PACKED){
          const unsigned int* vrow = vtph + (size_t)(16*n + lr) * S + kc + 32*ks + lg*8;
          uint4 pv0 = *reinterpret_cast<const uint4*>(vrow);
          uint4 pv1 = *reinterpret_cast<const uint4*>(vrow + 4);
          unsigned int pw[8] = {pv0.x,pv0.y,pv0.z,pv0.w,pv1.x,pv1.y,pv1.z,pv1.w};
#pragma unroll
          for (int j = 0; j < 8; ++j){
            bhi[j] = (short)(pw[j] >> 16);
            blo[j] = (short)(pw[j] & 0xFFFFu);
          }
        } else {
#pragma unroll
          for (int j = 0; j < 8; ++j){
            float x = vh[(size_t)(kc + 32*ks + lg*8 + j) * DD + 16*n + lr];
            short h, l2; split2(x, h, l2);
            bhi[j] = h; blo[j] = l2;
          }
        }
        oacc[n] = __builtin_amdgcn_mfma_f32_16x16x32_bf16(alo, bhi, oacc[n], 0,0,0);
        oacc[n] = __builtin_amdgcn_mfma_f32_16x16x32_bf16(ahi, blo, oacc[n], 0,0,0);
        oacc[n] = __builtin_amdgcn_mfma_f32_16x16x32_bf16(ahi, bhi, oacc[n], 0,0,0);
      }
    }
    __syncthreads();   // slab consumed; safe to refill
  }

  // cross-wave reduction of out partials (alias sW)
  float (*sO)[16][68] = reinterpret_cast<float(*)[16][68]>(sW);
#pragma unroll
  for (int n = 0; n < 4; ++n)
#pragma unroll
    for (int r = 0; r < 4; ++r)
      sO[wid][lg*4 + r][16*n + lr] = oacc[n][r];
  __syncthreads();
#pragma unroll
  for (int i = tid; i < 16*64; i += 512){
    int row = i >> 6, d = i & 63;
    float ssum = 0.f;
#pragma unroll
    for (int wv = 0; wv < NW; ++wv) ssum += sO[wv][row][d];
    __builtin_nontemporal_store(ssum, &oh[(size_t)(q0 + row) * DD + d]);
  }
}

extern "C" void kernel_launch(void* const* d_in, const int* in_sizes, int n_in,
                              void* d_out, int out_size, void* d_ws, size_t ws_size,
                              hipStream_t stream) {
  const float* q    = (const float*)d_in[0];
  const float* k    = (const float*)d_in[1];
  const float* v    = (const float*)d_in[2];
  const float* bias = (const float*)d_in[3];
  const float* gb   = (const float*)d_in[4];
  float* out  = (float*)d_out;
  float* wout = (float*)d_out + (size_t)NH * S * DD;

  const size_t nelem = (size_t)NH * S * DD;       // 4.19M
  const size_t need  = 2 * nelem * sizeof(unsigned int);

  dim3 gridT(S / 16, NH);
  dim3 block512(512);

  if (ws_size >= need){
    unsigned int* kp  = (unsigned int*)d_ws;
    unsigned int* vtp = kp + nelem;
    int n4 = (int)(nelem / 4);
    pack_k_kernel<<<(n4 + 255) / 256, 256, 0, stream>>>(k, kp, n4);
    pack_vt_kernel<<<NH * 32, 256, 0, stream>>>(v, vtp);
    qk_scores_kernel<true ><<<gridT, block512, 0, stream>>>(q, k, kp, wout);
    softmax_row_kernel<<<NH * S, 256, 0, stream>>>(bias, gb, wout);
    pv_kernel<true ><<<gridT, block512, 0, stream>>>(wout, v, vtp, out);
  } else {
    qk_scores_kernel<false><<<gridT, block512, 0, stream>>>(q, k, nullptr, wout);
    softmax_row_kernel<<<NH * S, 256, 0, stream>>>(bias, gb, wout);
    pv_kernel<false><<<gridT, block512, 0, stream>>>(wout, v, nullptr, out);
  }
}

// Round 20
// 1138.183 us; speedup vs baseline: 1.2467x; 1.0381x over previous
//
#include <hip/hip_runtime.h>

#define S 2048
#define DD 64
#define NH 32           // B*H
#define NW 8            // waves per block
#define KSLICE 256      // k columns per wave
#define NT 16           // 16-wide k tiles per wave

typedef float f32x4 __attribute__((ext_vector_type(4)));
typedef float f32x2 __attribute__((ext_vector_type(2)));
typedef unsigned int u32x4 __attribute__((ext_vector_type(4)));
typedef short bf16x8 __attribute__((ext_vector_type(8)));

__device__ inline unsigned int packsplit(float x){
  unsigned int u = __float_as_uint(x);
  unsigned int h = u >> 16;
  float rem = x - __uint_as_float(h << 16);
  unsigned int l = __float_as_uint(rem) >> 16;
  return (h << 16) | l;
}
__device__ inline void split2(float x, short &hi, short &lo){
  unsigned int p = packsplit(x);
  hi = (short)(p >> 16); lo = (short)(p & 0xFFFFu);
}
__device__ inline f32x4 ntload4(const float* p){
  return __builtin_nontemporal_load(reinterpret_cast<const f32x4*>(p));
}
__device__ inline void ntstore4(float* p, f32x4 v){
  __builtin_nontemporal_store(v, reinterpret_cast<f32x4*>(p));
}
// wave-local LDS ordering fence (st buffers are wave-private; lgkmcnt counts
// this wave's DS ops; sched_barrier stops hipcc reordering around it - rule #18)
__device__ inline void wave_lds_fence(){
  asm volatile("s_waitcnt lgkmcnt(0)" ::: "memory");
  __builtin_amdgcn_sched_barrier(0);
}

// ---- pre-pack kernels ----
__global__ void pack_k_kernel(const float* __restrict__ in, unsigned int* __restrict__ out, int n4){
  int i = blockIdx.x * 256 + threadIdx.x;
  if (i < n4){
    f32x4 x = ntload4(in + 4*(size_t)i);
    u32x4 p;
    p.x = packsplit(x.x); p.y = packsplit(x.y);
    p.z = packsplit(x.z); p.w = packsplit(x.w);
    reinterpret_cast<u32x4*>(out)[i] = p;
  }
}

__global__ void pack_vt_kernel(const float* __restrict__ v, unsigned int* __restrict__ vt){
  const int head = blockIdx.x >> 5;
  const int s0   = (blockIdx.x & 31) * 64;
  const float* vh = v + (size_t)head * S * DD;
  unsigned int* vth = vt + (size_t)head * DD * S;
  __shared__ unsigned int tile[64][65];
  const int tid = threadIdx.x;
  for (int i = tid; i < 64*64; i += 256){
    int s = i >> 6, d = i & 63;
    tile[d][s] = packsplit(__builtin_nontemporal_load(&vh[(size_t)(s0 + s) * DD + d]));
  }
  __syncthreads();
  for (int i = tid; i < 64*64; i += 256){
    int d = i >> 6, s = i & 63;
    vth[(size_t)d * S + s0 + s] = tile[d][s];
  }
}

// ==== K1: QK^T -> scores in standard layout via wave-private LDS transpose.
// Stores: 1KB contiguous single-row runs. Transpose ordering is WAVE-LOCAL
// (explicit lgkmcnt fences) - no block barriers, waves fully decoupled. ====
template<bool PACKED>
__global__ __launch_bounds__(512, 4)
void qk_scores_kernel(const float* __restrict__ q, const float* __restrict__ k,
                      const unsigned int* __restrict__ kp, float* __restrict__ sc)
{
  const int head = blockIdx.y;
  const int q0   = blockIdx.x * 16;
  const int tid  = threadIdx.x;
  const int wid  = tid >> 6;
  const int lane = tid & 63;
  const int lr   = lane & 15;
  const int lg   = lane >> 4;

  const float* qh = q + (size_t)head * S * DD;
  const float* kh = k + (size_t)head * S * DD;
  const unsigned int* kph = kp + (size_t)head * S * DD;
  float* sh = sc + (size_t)head * S * S;

  __shared__ float st[NW][8][260];   // 66.6 KB: per-wave transpose buffer

  // Q fragments, pre-scaled by 1/sqrt(64)
  bf16x8 qhi[2], qlo[2];
  {
    const float* qrow = qh + (size_t)(q0 + lr) * DD;
#pragma unroll
    for (int ks = 0; ks < 2; ++ks){
      float4 a = *reinterpret_cast<const float4*>(qrow + ks*32 + lg*8);
      float4 b = *reinterpret_cast<const float4*>(qrow + ks*32 + lg*8 + 4);
      float f[8] = {a.x,a.y,a.z,a.w,b.x,b.y,b.z,b.w};
#pragma unroll
      for (int j = 0; j < 8; ++j){
        short h, l2; split2(f[j] * 0.125f, h, l2);
        qhi[ks][j] = h; qlo[ks][j] = l2;
      }
    }
  }

  const int kw0 = wid * KSLICE;
  f32x4 acc[NT];
#pragma unroll
  for (int t = 0; t < NT; ++t) acc[t] = (f32x4){0.f,0.f,0.f,0.f};

#pragma unroll 2
  for (int t = 0; t < NT; ++t){
    const int kbase = kw0 + 16*t;
    bf16x8 khi[2], klo[2];
    if constexpr (PACKED){
      const unsigned int* kr = kph + (size_t)(kbase + lr) * DD;
#pragma unroll
      for (int ks = 0; ks < 2; ++ks){
        uint4 pa = *reinterpret_cast<const uint4*>(kr + ks*32 + lg*8);
        uint4 pb = *reinterpret_cast<const uint4*>(kr + ks*32 + lg*8 + 4);
        unsigned int pw[8] = {pa.x,pa.y,pa.z,pa.w,pb.x,pb.y,pb.z,pb.w};
#pragma unroll
        for (int j = 0; j < 8; ++j){
          khi[ks][j] = (short)(pw[j] >> 16);
          klo[ks][j] = (short)(pw[j] & 0xFFFFu);
        }
      }
    } else {
      const float* krow = kh + (size_t)(kbase + lr) * DD;
#pragma unroll
      for (int ks = 0; ks < 2; ++ks){
        float4 a = *reinterpret_cast<const float4*>(krow + ks*32 + lg*8);
        float4 b = *reinterpret_cast<const float4*>(krow + ks*32 + lg*8 + 4);
        float f[8] = {a.x,a.y,a.z,a.w,b.x,b.y,b.z,b.w};
#pragma unroll
        for (int j = 0; j < 8; ++j){
          short h, l2; split2(f[j], h, l2);
          khi[ks][j] = h; klo[ks][j] = l2;
        }
      }
    }
#pragma unroll
    for (int ks = 0; ks < 2; ++ks){
      acc[t] = __builtin_amdgcn_mfma_f32_16x16x32_bf16(klo[ks], qhi[ks], acc[t], 0,0,0);
      acc[t] = __builtin_amdgcn_mfma_f32_16x16x32_bf16(khi[ks], qlo[ks], acc[t], 0,0,0);
      acc[t] = __builtin_amdgcn_mfma_f32_16x16x32_bf16(khi[ks], qhi[ks], acc[t], 0,0,0);
    }
  }

  // ---- wave-private transpose dump: two 8-row passes, wave-local fences.
#pragma unroll 1
  for (int p = 0; p < 2; ++p){
    if ((lr >> 3) == p){
#pragma unroll
      for (int t = 0; t < NT; ++t)
        *reinterpret_cast<f32x4*>(&st[wid][lr & 7][16*t + lg*4]) = acc[t];
    }
    wave_lds_fence();                 // masked ds_writes done (wave-ordered)
#pragma unroll
    for (int j = 0; j < 8; ++j){
      const int row8 = (j + wid) & 7;
      f32x4 v4 = *reinterpret_cast<const f32x4*>(&st[wid][row8][lane*4]);
      ntstore4(sh + (size_t)(q0 + p*8 + row8) * S + wid*256 + lane*4, v4);
    }
    wave_lds_fence();                 // ds_reads done before next-pass rewrite
  }
}

// ==== K2: row softmax of (scores + bias - 0.5*g^2), in-place on w ====
__global__ __launch_bounds__(256, 8)
void softmax_row_kernel(const float* __restrict__ bias, const float* __restrict__ gb,
                        float* __restrict__ w)
{
  const int bid  = (NH * S - 1) - (int)blockIdx.x;   // reverse: catch K1's L3-warm tail
  const int head = bid >> 11;
  const int row  = bid & (S - 1);
  const size_t ro = ((size_t)head * S + row) * S;
  const int tid  = threadIdx.x;
  const int wid  = tid >> 6;
  const int lane = tid & 63;
  const int c0   = tid * 8;

  f32x4 s0 = *reinterpret_cast<const f32x4*>(w + ro + c0);
  f32x4 s1 = *reinterpret_cast<const f32x4*>(w + ro + c0 + 4);
  f32x4 b0 = ntload4(bias + ro + c0);
  f32x4 b1 = ntload4(bias + ro + c0 + 4);
  f32x4 g0 = ntload4(gb + ro + c0);
  f32x4 g1 = ntload4(gb + ro + c0 + 4);

  float x[8];
#pragma unroll
  for (int j = 0; j < 4; ++j){
    x[j]   = s0[j] + b0[j] - 0.5f * g0[j] * g0[j];
    x[4+j] = s1[j] + b1[j] - 0.5f * g1[j] * g1[j];
  }

  __shared__ float redm[4], reds[4];

  float m = x[0];
#pragma unroll
  for (int j = 1; j < 8; ++j) m = fmaxf(m, x[j]);
#pragma unroll
  for (int off = 1; off < 64; off <<= 1) m = fmaxf(m, __shfl_xor(m, off, 64));
  if (lane == 0) redm[wid] = m;
  __syncthreads();
  m = fmaxf(fmaxf(redm[0], redm[1]), fmaxf(redm[2], redm[3]));

  float e[8], s = 0.f;
#pragma unroll
  for (int j = 0; j < 8; ++j){ e[j] = __expf(x[j] - m); s += e[j]; }
#pragma unroll
  for (int off = 1; off < 64; off <<= 1) s += __shfl_xor(s, off, 64);
  if (lane == 0) reds[wid] = s;
  __syncthreads();
  const float inv = 1.0f / (reds[0] + reds[1] + reds[2] + reds[3]);

  f32x4 w0, w1;
#pragma unroll
  for (int j = 0; j < 4; ++j){ w0[j] = e[j] * inv; w1[j] = e[4+j] * inv; }
  *reinterpret_cast<f32x4*>(w + ro + c0)     = w0;
  *reinterpret_cast<f32x4*>(w + ro + c0 + 4) = w1;
}

// ==== K3: out = W x V, wave-independent. Each wave streams its 16x128
// half-slice contiguously (512B/instr) into wave-private LDS, extracts MFMA
// A-fragments directly (8 consecutive floats -> split2 in regs). No slab,
// no sW, no block barriers until the final reduction. ====
template<bool PACKED>
__global__ __launch_bounds__(512, 4)
void pv_kernel(const float* __restrict__ w, const float* __restrict__ v,
               const unsigned int* __restrict__ vtp, float* __restrict__ out)
{
  const int head = (NH - 1) - blockIdx.y;            // reverse: catch K2's L3 tail
  const int q0   = ((S/16 - 1) - blockIdx.x) * 16;
  const int tid  = threadIdx.x;
  const int wid  = tid >> 6;
  const int lane = tid & 63;
  const int lr   = lane & 15;
  const int lg   = lane >> 4;

  const float* wh = w + (size_t)head * S * S;
  const float* vh = v + (size_t)head * S * DD;
  const unsigned int* vtph = vtp + (size_t)head * DD * S;
  float* oh = out + (size_t)head * S * DD;

  __shared__ float buf[NW][16][132];                 // 67.6 KB wave-private

  const int kw0 = wid * KSLICE;
  f32x4 oacc[4];
#pragma unroll
  for (int n = 0; n < 4; ++n) oacc[n] = (f32x4){0.f,0.f,0.f,0.f};

#pragma unroll 1
  for (int h = 0; h < 2; ++h){
    const int colbase = kw0 + 128*h;
    // contiguous fill: one instruction = 64 lanes x 8B = 512B in ONE row
#pragma unroll
    for (int rr = 0; rr < 16; ++rr){
      f32x2 x = *reinterpret_cast<const f32x2*>(
          wh + (size_t)(q0 + rr) * S + colbase + 2*lane);
      *reinterpret_cast<f32x2*>(&buf[wid][rr][2*lane]) = x;
    }
    wave_lds_fence();

#pragma unroll
    for (int c2 = 0; c2 < 2; ++c2){
      const int kc = colbase + 64*c2;
#pragma unroll
      for (int ks = 0; ks < 2; ++ks){
        f32x4 wa = *reinterpret_cast<const f32x4*>(&buf[wid][lr][64*c2 + 32*ks + lg*8]);
        f32x4 wb = *reinterpret_cast<const f32x4*>(&buf[wid][lr][64*c2 + 32*ks + lg*8 + 4]);
        float f[8] = {wa[0],wa[1],wa[2],wa[3],wb[0],wb[1],wb[2],wb[3]};
        bf16x8 ahi, alo;
#pragma unroll
        for (int j = 0; j < 8; ++j){
          short hh, ll; split2(f[j], hh, ll);
          ahi[j] = hh; alo[j] = ll;
        }
#pragma unroll
        for (int n = 0; n < 4; ++n){
          bf16x8 bhi, blo;
          if constexpr (PACKED){
            const unsigned int* vrow = vtph + (size_t)(16*n + lr) * S + kc + 32*ks + lg*8;
            uint4 pv0 = *reinterpret_cast<const uint4*>(vrow);
            uint4 pv1 = *reinterpret_cast<const uint4*>(vrow + 4);
            unsigned int pw[8] = {pv0.x,pv0.y,pv0.z,pv0.w,pv1.x,pv1.y,pv1.z,pv1.w};
#pragma unroll
            for (int j = 0; j < 8; ++j){
              bhi[j] = (short)(pw[j] >> 16);
              blo[j] = (short)(pw[j] & 0xFFFFu);
            }
          } else {
#pragma unroll
            for (int j = 0; j < 8; ++j){
              float x = vh[(size_t)(kc + 32*ks + lg*8 + j) * DD + 16*n + lr];
              short hh, ll; split2(x, hh, ll);
              bhi[j] = hh; blo[j] = ll;
            }
          }
          oacc[n] = __builtin_amdgcn_mfma_f32_16x16x32_bf16(alo, bhi, oacc[n], 0,0,0);
          oacc[n] = __builtin_amdgcn_mfma_f32_16x16x32_bf16(ahi, blo, oacc[n], 0,0,0);
          oacc[n] = __builtin_amdgcn_mfma_f32_16x16x32_bf16(ahi, bhi, oacc[n], 0,0,0);
        }
      }
    }
    wave_lds_fence();   // frag reads done before next-half rewrite
  }

  // cross-wave reduction of out partials (alias buf)
  float (*sO)[16][68] = reinterpret_cast<float(*)[16][68]>(&buf[0][0][0]);
  __syncthreads();
#pragma unroll
  for (int n = 0; n < 4; ++n)
#pragma unroll
    for (int r = 0; r < 4; ++r)
      sO[wid][lg*4 + r][16*n + lr] = oacc[n][r];
  __syncthreads();
#pragma unroll
  for (int i = tid; i < 16*64; i += 512){
    int row = i >> 6, d = i & 63;
    float ssum = 0.f;
#pragma unroll
    for (int wv = 0; wv < NW; ++wv) ssum += sO[wv][row][d];
    __builtin_nontemporal_store(ssum, &oh[(size_t)(q0 + row) * DD + d]);
  }
}

extern "C" void kernel_launch(void* const* d_in, const int* in_sizes, int n_in,
                              void* d_out, int out_size, void* d_ws, size_t ws_size,
                              hipStream_t stream) {
  const float* q    = (const float*)d_in[0];
  const float* k    = (const float*)d_in[1];
  const float* v    = (const float*)d_in[2];
  const float* bias = (const float*)d_in[3];
  const float* gb   = (const float*)d_in[4];
  float* out  = (float*)d_out;
  float* wout = (float*)d_out + (size_t)NH * S * DD;

  const size_t nelem = (size_t)NH * S * DD;       // 4.19M
  const size_t need  = 2 * nelem * sizeof(unsigned int);

  dim3 gridT(S / 16, NH);
  dim3 block512(512);

  if (ws_size >= need){
    unsigned int* kp  = (unsigned int*)d_ws;
    unsigned int* vtp = kp + nelem;
    int n4 = (int)(nelem / 4);
    pack_k_kernel<<<(n4 + 255) / 256, 256, 0, stream>>>(k, kp, n4);
    pack_vt_kernel<<<NH * 32, 256, 0, stream>>>(v, vtp);
    qk_scores_kernel<true ><<<gridT, block512, 0, stream>>>(q, k, kp, wout);
    softmax_row_kernel<<<NH * S, 256, 0, stream>>>(bias, gb, wout);
    pv_kernel<true ><<<gridT, block512, 0, stream>>>(wout, v, vtp, out);
  } else {
    qk_scores_kernel<false><<<gridT, block512, 0, stream>>>(q, k, nullptr, wout);
    softmax_row_kernel<<<NH * S, 256, 0, stream>>>(bias, gb, wout);
    pv_kernel<false><<<gridT, block512, 0, stream>>>(wout, v, nullptr, out);
  }
}

// Round 21
// 1103.912 us; speedup vs baseline: 1.2854x; 1.0310x over previous
//
#include <hip/hip_runtime.h>

#define S 2048
#define DD 64
#define NH 32           // B*H
#define NW 8            // waves per block
#define KSLICE 256      // k columns per wave
#define NT 16           // 16-wide k tiles per wave

typedef float f32x4 __attribute__((ext_vector_type(4)));
typedef float f32x2 __attribute__((ext_vector_type(2)));
typedef unsigned int u32x4 __attribute__((ext_vector_type(4)));
typedef short bf16x8 __attribute__((ext_vector_type(8)));
typedef _Float16 f16x4 __attribute__((ext_vector_type(4)));
typedef _Float16 f16x8 __attribute__((ext_vector_type(8)));

__device__ inline unsigned int packsplit(float x){
  unsigned int u = __float_as_uint(x);
  unsigned int h = u >> 16;
  float rem = x - __uint_as_float(h << 16);
  unsigned int l = __float_as_uint(rem) >> 16;
  return (h << 16) | l;
}
__device__ inline void split2(float x, short &hi, short &lo){
  unsigned int p = packsplit(x);
  hi = (short)(p >> 16); lo = (short)(p & 0xFFFFu);
}
__device__ inline f32x4 ntload4(const float* p){
  return __builtin_nontemporal_load(reinterpret_cast<const f32x4*>(p));
}
// wave-local LDS ordering fence (st buffers are wave-private; lgkmcnt counts
// this wave's DS ops; sched_barrier stops hipcc reordering around it)
__device__ inline void wave_lds_fence(){
  asm volatile("s_waitcnt lgkmcnt(0)" ::: "memory");
  __builtin_amdgcn_sched_barrier(0);
}

// ---- pre-pack kernels ----
__global__ void pack_k_kernel(const float* __restrict__ in, unsigned int* __restrict__ out, int n4){
  int i = blockIdx.x * 256 + threadIdx.x;
  if (i < n4){
    f32x4 x = ntload4(in + 4*(size_t)i);
    u32x4 p;
    p.x = packsplit(x.x); p.y = packsplit(x.y);
    p.z = packsplit(x.z); p.w = packsplit(x.w);
    reinterpret_cast<u32x4*>(out)[i] = p;
  }
}

__global__ void pack_vt_kernel(const float* __restrict__ v, unsigned int* __restrict__ vt){
  const int head = blockIdx.x >> 5;
  const int s0   = (blockIdx.x & 31) * 64;
  const float* vh = v + (size_t)head * S * DD;
  unsigned int* vth = vt + (size_t)head * DD * S;
  __shared__ unsigned int tile[64][65];
  const int tid = threadIdx.x;
  for (int i = tid; i < 64*64; i += 256){
    int s = i >> 6, d = i & 63;
    tile[d][s] = packsplit(__builtin_nontemporal_load(&vh[(size_t)(s0 + s) * DD + d]));
  }
  __syncthreads();
  for (int i = tid; i < 64*64; i += 256){
    int d = i >> 6, s = i & 63;
    vth[(size_t)d * S + s0 + s] = tile[d][s];
  }
}

// ==== K1: QK^T -> fp16 scores stored in the FIRST 4KB of each row's 8KB
// weight slot (K2 block for row r reads+overwrites only its own slot:
// race-free, no dispatch-order assumptions). Fresh-write bytes halved. ====
template<bool PACKED>
__global__ __launch_bounds__(512, 4)
void qk_scores_kernel(const float* __restrict__ q, const float* __restrict__ k,
                      const unsigned int* __restrict__ kp, float* __restrict__ sc)
{
  const int head = blockIdx.y;
  const int q0   = blockIdx.x * 16;
  const int tid  = threadIdx.x;
  const int wid  = tid >> 6;
  const int lane = tid & 63;
  const int lr   = lane & 15;
  const int lg   = lane >> 4;

  const float* qh = q + (size_t)head * S * DD;
  const float* kh = k + (size_t)head * S * DD;
  const unsigned int* kph = kp + (size_t)head * S * DD;
  float* sh = sc + (size_t)head * S * S;

  __shared__ float st[NW][8][260];   // 66.6 KB: per-wave transpose buffer

  // Q fragments, pre-scaled by 1/sqrt(64)
  bf16x8 qhi[2], qlo[2];
  {
    const float* qrow = qh + (size_t)(q0 + lr) * DD;
#pragma unroll
    for (int ks = 0; ks < 2; ++ks){
      float4 a = *reinterpret_cast<const float4*>(qrow + ks*32 + lg*8);
      float4 b = *reinterpret_cast<const float4*>(qrow + ks*32 + lg*8 + 4);
      float f[8] = {a.x,a.y,a.z,a.w,b.x,b.y,b.z,b.w};
#pragma unroll
      for (int j = 0; j < 8; ++j){
        short h, l2; split2(f[j] * 0.125f, h, l2);
        qhi[ks][j] = h; qlo[ks][j] = l2;
      }
    }
  }

  const int kw0 = wid * KSLICE;
  f32x4 acc[NT];
#pragma unroll
  for (int t = 0; t < NT; ++t) acc[t] = (f32x4){0.f,0.f,0.f,0.f};

#pragma unroll 2
  for (int t = 0; t < NT; ++t){
    const int kbase = kw0 + 16*t;
    bf16x8 khi[2], klo[2];
    if constexpr (PACKED){
      const unsigned int* kr = kph + (size_t)(kbase + lr) * DD;
#pragma unroll
      for (int ks = 0; ks < 2; ++ks){
        uint4 pa = *reinterpret_cast<const uint4*>(kr + ks*32 + lg*8);
        uint4 pb = *reinterpret_cast<const uint4*>(kr + ks*32 + lg*8 + 4);
        unsigned int pw[8] = {pa.x,pa.y,pa.z,pa.w,pb.x,pb.y,pb.z,pb.w};
#pragma unroll
        for (int j = 0; j < 8; ++j){
          khi[ks][j] = (short)(pw[j] >> 16);
          klo[ks][j] = (short)(pw[j] & 0xFFFFu);
        }
      }
    } else {
      const float* krow = kh + (size_t)(kbase + lr) * DD;
#pragma unroll
      for (int ks = 0; ks < 2; ++ks){
        float4 a = *reinterpret_cast<const float4*>(krow + ks*32 + lg*8);
        float4 b = *reinterpret_cast<const float4*>(krow + ks*32 + lg*8 + 4);
        float f[8] = {a.x,a.y,a.z,a.w,b.x,b.y,b.z,b.w};
#pragma unroll
        for (int j = 0; j < 8; ++j){
          short h, l2; split2(f[j], h, l2);
          khi[ks][j] = h; klo[ks][j] = l2;
        }
      }
    }
#pragma unroll
    for (int ks = 0; ks < 2; ++ks){
      acc[t] = __builtin_amdgcn_mfma_f32_16x16x32_bf16(klo[ks], qhi[ks], acc[t], 0,0,0);
      acc[t] = __builtin_amdgcn_mfma_f32_16x16x32_bf16(khi[ks], qlo[ks], acc[t], 0,0,0);
      acc[t] = __builtin_amdgcn_mfma_f32_16x16x32_bf16(khi[ks], qhi[ks], acc[t], 0,0,0);
    }
  }

  // ---- wave-private transpose dump, wave-local fences, fp16 output.
  // One store instruction = 64 lanes x 8B = 512B contiguous in ONE row slot.
#pragma unroll 1
  for (int p = 0; p < 2; ++p){
    if ((lr >> 3) == p){
#pragma unroll
      for (int t = 0; t < NT; ++t)
        *reinterpret_cast<f32x4*>(&st[wid][lr & 7][16*t + lg*4]) = acc[t];
    }
    wave_lds_fence();                 // masked ds_writes done (wave-ordered)
#pragma unroll
    for (int j = 0; j < 8; ++j){
      const int row8 = (j + wid) & 7;
      f32x4 v4 = *reinterpret_cast<const f32x4*>(&st[wid][row8][lane*4]);
      f16x4 hv;
#pragma unroll
      for (int r = 0; r < 4; ++r) hv[r] = (_Float16)v4[r];
      _Float16* dst = reinterpret_cast<_Float16*>(
          sh + (size_t)(q0 + p*8 + row8) * S) + wid*256 + lane*4;
      *reinterpret_cast<f16x4*>(dst) = hv;
    }
    wave_lds_fence();                 // ds_reads done before next-pass rewrite
  }
}

// ==== K2: row softmax of (fp16 scores + bias - 0.5*g^2); reads the fp16
// scores from the first 4KB of its own weight slot, overwrites the slot
// with fp32 weights (read-before-write within block: race-free). ====
__global__ __launch_bounds__(256, 8)
void softmax_row_kernel(const float* __restrict__ bias, const float* __restrict__ gb,
                        float* __restrict__ w)
{
  const int bid  = (NH * S - 1) - (int)blockIdx.x;   // reverse: catch K1's L3-warm tail
  const int head = bid >> 11;
  const int row  = bid & (S - 1);
  const size_t ro = ((size_t)head * S + row) * S;
  const int tid  = threadIdx.x;
  const int wid  = tid >> 6;
  const int lane = tid & 63;
  const int c0   = tid * 8;

  const _Float16* sp = reinterpret_cast<const _Float16*>(w + ro);
  f16x8 sv = *reinterpret_cast<const f16x8*>(sp + c0);
  f32x4 b0 = ntload4(bias + ro + c0);
  f32x4 b1 = ntload4(bias + ro + c0 + 4);
  f32x4 g0 = ntload4(gb + ro + c0);
  f32x4 g1 = ntload4(gb + ro + c0 + 4);

  float x[8];
#pragma unroll
  for (int j = 0; j < 4; ++j){
    x[j]   = (float)sv[j]   + b0[j] - 0.5f * g0[j] * g0[j];
    x[4+j] = (float)sv[4+j] + b1[j] - 0.5f * g1[j] * g1[j];
  }

  __shared__ float redm[4], reds[4];

  float m = x[0];
#pragma unroll
  for (int j = 1; j < 8; ++j) m = fmaxf(m, x[j]);
#pragma unroll
  for (int off = 1; off < 64; off <<= 1) m = fmaxf(m, __shfl_xor(m, off, 64));
  if (lane == 0) redm[wid] = m;
  __syncthreads();
  m = fmaxf(fmaxf(redm[0], redm[1]), fmaxf(redm[2], redm[3]));

  float e[8], s = 0.f;
#pragma unroll
  for (int j = 0; j < 8; ++j){ e[j] = __expf(x[j] - m); s += e[j]; }
#pragma unroll
  for (int off = 1; off < 64; off <<= 1) s += __shfl_xor(s, off, 64);
  if (lane == 0) reds[wid] = s;
  __syncthreads();
  const float inv = 1.0f / (reds[0] + reds[1] + reds[2] + reds[3]);

  f32x4 w0, w1;
#pragma unroll
  for (int j = 0; j < 4; ++j){ w0[j] = e[j] * inv; w1[j] = e[4+j] * inv; }
  *reinterpret_cast<f32x4*>(w + ro + c0)     = w0;
  *reinterpret_cast<f32x4*>(w + ro + c0 + 4) = w1;
}

// ==== K3: out = W x V, wave-independent, NATURAL order (K2 reversed ends
// at head 0 -> L3 warmest there; start where K2 finished). ====
template<bool PACKED>
__global__ __launch_bounds__(512, 4)
void pv_kernel(const float* __restrict__ w, const float* __restrict__ v,
               const unsigned int* __restrict__ vtp, float* __restrict__ out)
{
  const int head = blockIdx.y;
  const int q0   = blockIdx.x * 16;
  const int tid  = threadIdx.x;
  const int wid  = tid >> 6;
  const int lane = tid & 63;
  const int lr   = lane & 15;
  const int lg   = lane >> 4;

  const float* wh = w + (size_t)head * S * S;
  const float* vh = v + (size_t)head * S * DD;
  const unsigned int* vtph = vtp + (size_t)head * DD * S;
  float* oh = out + (size_t)head * S * DD;

  __shared__ float buf[NW][16][132];                 // 67.6 KB wave-private

  const int kw0 = wid * KSLICE;
  f32x4 oacc[4];
#pragma unroll
  for (int n = 0; n < 4; ++n) oacc[n] = (f32x4){0.f,0.f,0.f,0.f};

#pragma unroll 1
  for (int h = 0; h < 2; ++h){
    const int colbase = kw0 + 128*h;
    // contiguous fill: one instruction = 64 lanes x 8B = 512B in ONE row
#pragma unroll
    for (int rr = 0; rr < 16; ++rr){
      f32x2 x = *reinterpret_cast<const f32x2*>(
          wh + (size_t)(q0 + rr) * S + colbase + 2*lane);
      *reinterpret_cast<f32x2*>(&buf[wid][rr][2*lane]) = x;
    }
    wave_lds_fence();

#pragma unroll
    for (int c2 = 0; c2 < 2; ++c2){
      const int kc = colbase + 64*c2;
#pragma unroll
      for (int ks = 0; ks < 2; ++ks){
        f32x4 wa = *reinterpret_cast<const f32x4*>(&buf[wid][lr][64*c2 + 32*ks + lg*8]);
        f32x4 wb = *reinterpret_cast<const f32x4*>(&buf[wid][lr][64*c2 + 32*ks + lg*8 + 4]);
        float f[8] = {wa[0],wa[1],wa[2],wa[3],wb[0],wb[1],wb[2],wb[3]};
        bf16x8 ahi, alo;
#pragma unroll
        for (int j = 0; j < 8; ++j){
          short hh, ll; split2(f[j], hh, ll);
          ahi[j] = hh; alo[j] = ll;
        }
#pragma unroll
        for (int n = 0; n < 4; ++n){
          bf16x8 bhi, blo;
          if constexpr (PACKED){
            const unsigned int* vrow = vtph + (size_t)(16*n + lr) * S + kc + 32*ks + lg*8;
            uint4 pv0 = *reinterpret_cast<const uint4*>(vrow);
            uint4 pv1 = *reinterpret_cast<const uint4*>(vrow + 4);
            unsigned int pw[8] = {pv0.x,pv0.y,pv0.z,pv0.w,pv1.x,pv1.y,pv1.z,pv1.w};
#pragma unroll
            for (int j = 0; j < 8; ++j){
              bhi[j] = (short)(pw[j] >> 16);
              blo[j] = (short)(pw[j] & 0xFFFFu);
            }
          } else {
#pragma unroll
            for (int j = 0; j < 8; ++j){
              float x = vh[(size_t)(kc + 32*ks + lg*8 + j) * DD + 16*n + lr];
              short hh, ll; split2(x, hh, ll);
              bhi[j] = hh; blo[j] = ll;
            }
          }
          oacc[n] = __builtin_amdgcn_mfma_f32_16x16x32_bf16(alo, bhi, oacc[n], 0,0,0);
          oacc[n] = __builtin_amdgcn_mfma_f32_16x16x32_bf16(ahi, blo, oacc[n], 0,0,0);
          oacc[n] = __builtin_amdgcn_mfma_f32_16x16x32_bf16(ahi, bhi, oacc[n], 0,0,0);
        }
      }
    }
    wave_lds_fence();   // frag reads done before next-half rewrite
  }

  // cross-wave reduction of out partials (alias buf)
  float (*sO)[16][68] = reinterpret_cast<float(*)[16][68]>(&buf[0][0][0]);
  __syncthreads();
#pragma unroll
  for (int n = 0; n < 4; ++n)
#pragma unroll
    for (int r = 0; r < 4; ++r)
      sO[wid][lg*4 + r][16*n + lr] = oacc[n][r];
  __syncthreads();
#pragma unroll
  for (int i = tid; i < 16*64; i += 512){
    int row = i >> 6, d = i & 63;
    float ssum = 0.f;
#pragma unroll
    for (int wv = 0; wv < NW; ++wv) ssum += sO[wv][row][d];
    __builtin_nontemporal_store(ssum, &oh[(size_t)(q0 + row) * DD + d]);
  }
}

extern "C" void kernel_launch(void* const* d_in, const int* in_sizes, int n_in,
                              void* d_out, int out_size, void* d_ws, size_t ws_size,
                              hipStream_t stream) {
  const float* q    = (const float*)d_in[0];
  const float* k    = (const float*)d_in[1];
  const float* v    = (const float*)d_in[2];
  const float* bias = (const float*)d_in[3];
  const float* gb   = (const float*)d_in[4];
  float* out  = (float*)d_out;
  float* wout = (float*)d_out + (size_t)NH * S * DD;

  const size_t nelem = (size_t)NH * S * DD;       // 4.19M
  const size_t need  = 2 * nelem * sizeof(unsigned int);

  dim3 gridT(S / 16, NH);
  dim3 block512(512);

  if (ws_size >= need){
    unsigned int* kp  = (unsigned int*)d_ws;
    unsigned int* vtp = kp + nelem;
    int n4 = (int)(nelem / 4);
    pack_k_kernel<<<(n4 + 255) / 256, 256, 0, stream>>>(k, kp, n4);
    pack_vt_kernel<<<NH * 32, 256, 0, stream>>>(v, vtp);
    qk_scores_kernel<true ><<<gridT, block512, 0, stream>>>(q, k, kp, wout);
    softmax_row_kernel<<<NH * S, 256, 0, stream>>>(bias, gb, wout);
    pv_kernel<true ><<<gridT, block512, 0, stream>>>(wout, v, vtp, out);
  } else {
    qk_scores_kernel<false><<<gridT, block512, 0, stream>>>(q, k, nullptr, wout);
    softmax_row_kernel<<<NH * S, 256, 0, stream>>>(bias, gb, wout);
    pv_kernel<false><<<gridT, block512, 0, stream>>>(wout, v, nullptr, out);
  }
}

// Round 22
// 1086.726 us; speedup vs baseline: 1.3058x; 1.0158x over previous
//
#include <hip/hip_runtime.h>

#define S 2048
#define DD 64
#define NH 32           // B*H
#define NW 8            // waves per block
#define KSLICE 256      // k columns per wave
#define NT 16           // 16-wide k tiles per wave

typedef float f32x4 __attribute__((ext_vector_type(4)));
typedef float f32x2 __attribute__((ext_vector_type(2)));
typedef unsigned int u32x4 __attribute__((ext_vector_type(4)));
typedef short bf16x8 __attribute__((ext_vector_type(8)));
typedef _Float16 f16x4 __attribute__((ext_vector_type(4)));
typedef _Float16 f16x8 __attribute__((ext_vector_type(8)));

__device__ inline unsigned int packsplit(float x){
  unsigned int u = __float_as_uint(x);
  unsigned int h = u >> 16;
  float rem = x - __uint_as_float(h << 16);
  unsigned int l = __float_as_uint(rem) >> 16;
  return (h << 16) | l;
}
__device__ inline void split2(float x, short &hi, short &lo){
  unsigned int p = packsplit(x);
  hi = (short)(p >> 16); lo = (short)(p & 0xFFFFu);
}
__device__ inline f32x4 ntload4(const float* p){
  return __builtin_nontemporal_load(reinterpret_cast<const f32x4*>(p));
}
// wave-local LDS ordering fence (buffers are wave-private; lgkmcnt counts
// this wave's DS ops; sched_barrier stops hipcc reordering around it)
__device__ inline void wave_lds_fence(){
  asm volatile("s_waitcnt lgkmcnt(0)" ::: "memory");
  __builtin_amdgcn_sched_barrier(0);
}

// ---- pre-pack kernels ----
__global__ void pack_k_kernel(const float* __restrict__ in, unsigned int* __restrict__ out, int n4){
  int i = blockIdx.x * 256 + threadIdx.x;
  if (i < n4){
    f32x4 x = ntload4(in + 4*(size_t)i);
    u32x4 p;
    p.x = packsplit(x.x); p.y = packsplit(x.y);
    p.z = packsplit(x.z); p.w = packsplit(x.w);
    reinterpret_cast<u32x4*>(out)[i] = p;
  }
}

__global__ void pack_vt_kernel(const float* __restrict__ v, unsigned int* __restrict__ vt){
  const int head = blockIdx.x >> 5;
  const int s0   = (blockIdx.x & 31) * 64;
  const float* vh = v + (size_t)head * S * DD;
  unsigned int* vth = vt + (size_t)head * DD * S;
  __shared__ unsigned int tile[64][65];
  const int tid = threadIdx.x;
  for (int i = tid; i < 64*64; i += 256){
    int s = i >> 6, d = i & 63;
    tile[d][s] = packsplit(__builtin_nontemporal_load(&vh[(size_t)(s0 + s) * DD + d]));
  }
  __syncthreads();
  for (int i = tid; i < 64*64; i += 256){
    int d = i >> 6, s = i & 63;
    vth[(size_t)d * S + s0 + s] = tile[d][s];
  }
}

// ==== K1: QK^T -> fp16 scores in the first 4KB of each row's 8KB weight
// slot. SINGLE-PASS fp16 LDS transpose: 2 fences (was 4), unmasked b64
// writes, 16 back-to-back 512B contiguous stores. ====
template<bool PACKED>
__global__ __launch_bounds__(512, 4)
void qk_scores_kernel(const float* __restrict__ q, const float* __restrict__ k,
                      const unsigned int* __restrict__ kp, float* __restrict__ sc)
{
  const int head = blockIdx.y;
  const int q0   = blockIdx.x * 16;
  const int tid  = threadIdx.x;
  const int wid  = tid >> 6;
  const int lane = tid & 63;
  const int lr   = lane & 15;
  const int lg   = lane >> 4;

  const float* qh = q + (size_t)head * S * DD;
  const float* kh = k + (size_t)head * S * DD;
  const unsigned int* kph = kp + (size_t)head * S * DD;
  float* sh = sc + (size_t)head * S * S;

  __shared__ unsigned short st16[NW][16][260];   // 66.6 KB fp16 transpose buf

  // Q fragments, pre-scaled by 1/sqrt(64)
  bf16x8 qhi[2], qlo[2];
  {
    const float* qrow = qh + (size_t)(q0 + lr) * DD;
#pragma unroll
    for (int ks = 0; ks < 2; ++ks){
      float4 a = *reinterpret_cast<const float4*>(qrow + ks*32 + lg*8);
      float4 b = *reinterpret_cast<const float4*>(qrow + ks*32 + lg*8 + 4);
      float f[8] = {a.x,a.y,a.z,a.w,b.x,b.y,b.z,b.w};
#pragma unroll
      for (int j = 0; j < 8; ++j){
        short h, l2; split2(f[j] * 0.125f, h, l2);
        qhi[ks][j] = h; qlo[ks][j] = l2;
      }
    }
  }

  const int kw0 = wid * KSLICE;
  f32x4 acc[NT];
#pragma unroll
  for (int t = 0; t < NT; ++t) acc[t] = (f32x4){0.f,0.f,0.f,0.f};

#pragma unroll 2
  for (int t = 0; t < NT; ++t){
    const int kbase = kw0 + 16*t;
    bf16x8 khi[2], klo[2];
    if constexpr (PACKED){
      const unsigned int* kr = kph + (size_t)(kbase + lr) * DD;
#pragma unroll
      for (int ks = 0; ks < 2; ++ks){
        uint4 pa = *reinterpret_cast<const uint4*>(kr + ks*32 + lg*8);
        uint4 pb = *reinterpret_cast<const uint4*>(kr + ks*32 + lg*8 + 4);
        unsigned int pw[8] = {pa.x,pa.y,pa.z,pa.w,pb.x,pb.y,pb.z,pb.w};
#pragma unroll
        for (int j = 0; j < 8; ++j){
          khi[ks][j] = (short)(pw[j] >> 16);
          klo[ks][j] = (short)(pw[j] & 0xFFFFu);
        }
      }
    } else {
      const float* krow = kh + (size_t)(kbase + lr) * DD;
#pragma unroll
      for (int ks = 0; ks < 2; ++ks){
        float4 a = *reinterpret_cast<const float4*>(krow + ks*32 + lg*8);
        float4 b = *reinterpret_cast<const float4*>(krow + ks*32 + lg*8 + 4);
        float f[8] = {a.x,a.y,a.z,a.w,b.x,b.y,b.z,b.w};
#pragma unroll
        for (int j = 0; j < 8; ++j){
          short h, l2; split2(f[j], h, l2);
          khi[ks][j] = h; klo[ks][j] = l2;
        }
      }
    }
#pragma unroll
    for (int ks = 0; ks < 2; ++ks){
      acc[t] = __builtin_amdgcn_mfma_f32_16x16x32_bf16(klo[ks], qhi[ks], acc[t], 0,0,0);
      acc[t] = __builtin_amdgcn_mfma_f32_16x16x32_bf16(khi[ks], qlo[ks], acc[t], 0,0,0);
      acc[t] = __builtin_amdgcn_mfma_f32_16x16x32_bf16(khi[ks], qhi[ks], acc[t], 0,0,0);
    }
  }

  // ---- single-pass fp16 transpose: all lanes write all 16 tiles, one fence,
  // then 16 x 512B contiguous row stores.
#pragma unroll
  for (int t = 0; t < NT; ++t){
    f16x4 hv;
#pragma unroll
    for (int r = 0; r < 4; ++r) hv[r] = (_Float16)acc[t][r];
    *reinterpret_cast<f16x4*>(&st16[wid][lr][16*t + lg*4]) = hv;
  }
  wave_lds_fence();
#pragma unroll
  for (int j = 0; j < 16; ++j){
    const int row = (j + wid) & 15;        // stagger rows across waves
    f16x4 hv = *reinterpret_cast<const f16x4*>(&st16[wid][row][lane*4]);
    _Float16* dst = reinterpret_cast<_Float16*>(
        sh + (size_t)(q0 + row) * S) + wid*256 + lane*4;
    *reinterpret_cast<f16x4*>(dst) = hv;
  }
}

// ==== K2: row softmax of (fp16 scores + bias - 0.5*g^2); reads fp16 scores
// from its own slot, overwrites with fp32 weights (race-free in-place). ====
__global__ __launch_bounds__(256, 8)
void softmax_row_kernel(const float* __restrict__ bias, const float* __restrict__ gb,
                        float* __restrict__ w)
{
  const int bid  = (NH * S - 1) - (int)blockIdx.x;   // reverse: catch K1's L3-warm tail
  const int head = bid >> 11;
  const int row  = bid & (S - 1);
  const size_t ro = ((size_t)head * S + row) * S;
  const int tid  = threadIdx.x;
  const int wid  = tid >> 6;
  const int lane = tid & 63;
  const int c0   = tid * 8;

  const _Float16* sp = reinterpret_cast<const _Float16*>(w + ro);
  f16x8 sv = *reinterpret_cast<const f16x8*>(sp + c0);
  f32x4 b0 = ntload4(bias + ro + c0);
  f32x4 b1 = ntload4(bias + ro + c0 + 4);
  f32x4 g0 = ntload4(gb + ro + c0);
  f32x4 g1 = ntload4(gb + ro + c0 + 4);

  float x[8];
#pragma unroll
  for (int j = 0; j < 4; ++j){
    x[j]   = (float)sv[j]   + b0[j] - 0.5f * g0[j] * g0[j];
    x[4+j] = (float)sv[4+j] + b1[j] - 0.5f * g1[j] * g1[j];
  }

  __shared__ float redm[4], reds[4];

  float m = x[0];
#pragma unroll
  for (int j = 1; j < 8; ++j) m = fmaxf(m, x[j]);
#pragma unroll
  for (int off = 1; off < 64; off <<= 1) m = fmaxf(m, __shfl_xor(m, off, 64));
  if (lane == 0) redm[wid] = m;
  __syncthreads();
  m = fmaxf(fmaxf(redm[0], redm[1]), fmaxf(redm[2], redm[3]));

  float e[8], s = 0.f;
#pragma unroll
  for (int j = 0; j < 8; ++j){ e[j] = __expf(x[j] - m); s += e[j]; }
#pragma unroll
  for (int off = 1; off < 64; off <<= 1) s += __shfl_xor(s, off, 64);
  if (lane == 0) reds[wid] = s;
  __syncthreads();
  const float inv = 1.0f / (reds[0] + reds[1] + reds[2] + reds[3]);

  f32x4 w0, w1;
#pragma unroll
  for (int j = 0; j < 4; ++j){ w0[j] = e[j] * inv; w1[j] = e[4+j] * inv; }
  *reinterpret_cast<f32x4*>(w + ro + c0)     = w0;
  *reinterpret_cast<f32x4*>(w + ro + c0 + 4) = w1;
}

// ==== K3: out = W x V, wave-independent, 4x64-col chunks with 2-deep LDS
// rotation: chunk c+1's global loads issue BEFORE chunk c's MFMA (T14
// async-stage) so HBM latency hides under compute. ====
template<bool PACKED>
__global__ __launch_bounds__(512, 4)
void pv_kernel(const float* __restrict__ w, const float* __restrict__ v,
               const unsigned int* __restrict__ vtp, float* __restrict__ out)
{
  const int head = blockIdx.y;
  const int q0   = blockIdx.x * 16;
  const int tid  = threadIdx.x;
  const int wid  = tid >> 6;
  const int lane = tid & 63;
  const int lr   = lane & 15;
  const int lg   = lane >> 4;

  const float* wh = w + (size_t)head * S * S;
  const float* vh = v + (size_t)head * S * DD;
  const unsigned int* vtph = vtp + (size_t)head * DD * S;
  float* oh = out + (size_t)head * S * DD;

  __shared__ float buf[NW][2][16][68];               // 69.6 KB, 2-deep rotation

  const int kw0 = wid * KSLICE;
  const int prow = lane >> 5;                        // fill: 2 rows per instr
  const int pcol = (lane & 31) * 2;

  f32x4 oacc[4];
#pragma unroll
  for (int n = 0; n < 4; ++n) oacc[n] = (f32x4){0.f,0.f,0.f,0.f};

  f32x2 pre[8];
  // prefetch chunk 0
#pragma unroll
  for (int i = 0; i < 8; ++i)
    pre[i] = *reinterpret_cast<const f32x2*>(
        wh + (size_t)(q0 + 2*i + prow) * S + kw0 + pcol);

#pragma unroll 1
  for (int c = 0; c < 4; ++c){
    const int b = c & 1;
    // deposit chunk c into LDS (source regs force vmcnt waits on c's loads)
#pragma unroll
    for (int i = 0; i < 8; ++i)
      *reinterpret_cast<f32x2*>(&buf[wid][b][2*i + prow][pcol]) = pre[i];
    // issue chunk c+1 loads now; they fly during chunk c's MFMA
    if (c < 3){
#pragma unroll
      for (int i = 0; i < 8; ++i)
        pre[i] = *reinterpret_cast<const f32x2*>(
            wh + (size_t)(q0 + 2*i + prow) * S + kw0 + 64*(c+1) + pcol);
    }
    wave_lds_fence();

    const int kc = kw0 + 64*c;
#pragma unroll
    for (int ks = 0; ks < 2; ++ks){
      f32x4 wa = *reinterpret_cast<const f32x4*>(&buf[wid][b][lr][32*ks + lg*8]);
      f32x4 wb = *reinterpret_cast<const f32x4*>(&buf[wid][b][lr][32*ks + lg*8 + 4]);
      float f[8] = {wa[0],wa[1],wa[2],wa[3],wb[0],wb[1],wb[2],wb[3]};
      bf16x8 ahi, alo;
#pragma unroll
      for (int j = 0; j < 8; ++j){
        short hh, ll; split2(f[j], hh, ll);
        ahi[j] = hh; alo[j] = ll;
      }
#pragma unroll
      for (int n = 0; n < 4; ++n){
        bf16x8 bhi, blo;
        if constexpr (PACKED){
          const unsigned int* vrow = vtph + (size_t)(16*n + lr) * S + kc + 32*ks + lg*8;
          uint4 pv0 = *reinterpret_cast<const uint4*>(vrow);
          uint4 pv1 = *reinterpret_cast<const uint4*>(vrow + 4);
          unsigned int pw[8] = {pv0.x,pv0.y,pv0.z,pv0.w,pv1.x,pv1.y,pv1.z,pv1.w};
#pragma unroll
          for (int j = 0; j < 8; ++j){
            bhi[j] = (short)(pw[j] >> 16);
            blo[j] = (short)(pw[j] & 0xFFFFu);
          }
        } else {
#pragma unroll
          for (int j = 0; j < 8; ++j){
            float x = vh[(size_t)(kc + 32*ks + lg*8 + j) * DD + 16*n + lr];
            short hh, ll; split2(x, hh, ll);
            bhi[j] = hh; blo[j] = ll;
          }
        }
        oacc[n] = __builtin_amdgcn_mfma_f32_16x16x32_bf16(alo, bhi, oacc[n], 0,0,0);
        oacc[n] = __builtin_amdgcn_mfma_f32_16x16x32_bf16(ahi, blo, oacc[n], 0,0,0);
        oacc[n] = __builtin_amdgcn_mfma_f32_16x16x32_bf16(ahi, bhi, oacc[n], 0,0,0);
      }
    }
  }

  // cross-wave reduction of out partials (alias buf)
  float (*sO)[16][68] = reinterpret_cast<float(*)[16][68]>(&buf[0][0][0][0]);
  __syncthreads();
#pragma unroll
  for (int n = 0; n < 4; ++n)
#pragma unroll
    for (int r = 0; r < 4; ++r)
      sO[wid][lg*4 + r][16*n + lr] = oacc[n][r];
  __syncthreads();
#pragma unroll
  for (int i = tid; i < 16*64; i += 512){
    int row = i >> 6, d = i & 63;
    float ssum = 0.f;
#pragma unroll
    for (int wv = 0; wv < NW; ++wv) ssum += sO[wv][row][d];
    __builtin_nontemporal_store(ssum, &oh[(size_t)(q0 + row) * DD + d]);
  }
}

extern "C" void kernel_launch(void* const* d_in, const int* in_sizes, int n_in,
                              void* d_out, int out_size, void* d_ws, size_t ws_size,
                              hipStream_t stream) {
  const float* q    = (const float*)d_in[0];
  const float* k    = (const float*)d_in[1];
  const float* v    = (const float*)d_in[2];
  const float* bias = (const float*)d_in[3];
  const float* gb   = (const float*)d_in[4];
  float* out  = (float*)d_out;
  float* wout = (float*)d_out + (size_t)NH * S * DD;

  const size_t nelem = (size_t)NH * S * DD;       // 4.19M
  const size_t need  = 2 * nelem * sizeof(unsigned int);

  dim3 gridT(S / 16, NH);
  dim3 block512(512);

  if (ws_size >= need){
    unsigned int* kp  = (unsigned int*)d_ws;
    unsigned int* vtp = kp + nelem;
    int n4 = (int)(nelem / 4);
    pack_k_kernel<<<(n4 + 255) / 256, 256, 0, stream>>>(k, kp, n4);
    pack_vt_kernel<<<NH * 32, 256, 0, stream>>>(v, vtp);
    qk_scores_kernel<true ><<<gridT, block512, 0, stream>>>(q, k, kp, wout);
    softmax_row_kernel<<<NH * S, 256, 0, stream>>>(bias, gb, wout);
    pv_kernel<true ><<<gridT, block512, 0, stream>>>(wout, v, vtp, out);
  } else {
    qk_scores_kernel<false><<<gridT, block512, 0, stream>>>(q, k, nullptr, wout);
    softmax_row_kernel<<<NH * S, 256, 0, stream>>>(bias, gb, wout);
    pv_kernel<false><<<gridT, block512, 0, stream>>>(wout, v, nullptr, out);
  }
}